// Round 1
// baseline (789.575 us; speedup 1.0000x reference)
//
#include <hip/hip_runtime.h>
#include <hip/hip_bf16.h>
#include <math.h>

#define BB 2
#define QQ 300
#define TT 300
#define HH 256
#define WW 256
#define PP 12544
#define NSPLIT 8
#define KSPLIT (PP / NSPLIT)          // 1568
#define KSTEPS (KSPLIT / 32)          // 49

typedef __bf16 bf16_t;
typedef bf16_t bf16x8 __attribute__((ext_vector_type(8)));
typedef float floatx4 __attribute__((ext_vector_type(4)));

// ---------------- kernel 1: per-point bilinear offsets/weights ----------------
__global__ __launch_bounds__(256) void prep_kernel(const float* __restrict__ pts,
                                                   int4* __restrict__ off,
                                                   float4* __restrict__ wgt) {
    int idx = blockIdx.x * 256 + threadIdx.x;
    if (idx >= BB * PP) return;
    float px = pts[idx * 2 + 0];
    float py = pts[idx * 2 + 1];
    float x = px * WW - 0.5f;
    float y = py * HH - 0.5f;
    float x0f = floorf(x), y0f = floorf(y);
    float wx = x - x0f, wy = y - y0f;
    int x0 = (int)x0f, y0 = (int)y0f;
    int x1 = x0 + 1, y1 = y0 + 1;
    float vx0 = (x0 >= 0 && x0 < WW) ? 1.f : 0.f;
    float vx1 = (x1 >= 0 && x1 < WW) ? 1.f : 0.f;
    float vy0 = (y0 >= 0 && y0 < HH) ? 1.f : 0.f;
    float vy1 = (y1 >= 0 && y1 < HH) ? 1.f : 0.f;
    int cx0 = min(max(x0, 0), WW - 1), cx1 = min(max(x1, 0), WW - 1);
    int cy0 = min(max(y0, 0), HH - 1), cy1 = min(max(y1, 0), HH - 1);
    off[idx] = make_int4(cy0 * WW + cx0, cy0 * WW + cx1, cy1 * WW + cx0, cy1 * WW + cx1);
    wgt[idx] = make_float4((1.f - wy) * (1.f - wx) * vy0 * vx0,
                           (1.f - wy) * wx        * vy0 * vx1,
                           wy        * (1.f - wx) * vy1 * vx0,
                           wy        * wx         * vy1 * vx1);
}

// ---------------- kernel 2: point-sample all masks, emit bf16 rows + row sums ----------------
// grid: (QQ+TT, BB) blocks; one block owns one mask image (stays L1/L2-hot)
__global__ __launch_bounds__(256) void sample_kernel(
    const float* __restrict__ pred_masks, const float* __restrict__ tgt_masks,
    const int4* __restrict__ off, const float4* __restrict__ wgt,
    bf16_t* __restrict__ OM, bf16_t* __restrict__ SM, bf16_t* __restrict__ TM,
    float* __restrict__ RS_SP, float* __restrict__ RS_S, float* __restrict__ RS_T) {
    int b = blockIdx.y;
    int m = blockIdx.x;  // 0..QQ+TT-1
    int tid = threadIdx.x;
    const int4*  offb = off + b * PP;
    const float4* wb  = wgt + b * PP;
    bool is_pred = (m < QQ);
    const float* img;
    bf16_t* row0;
    bf16_t* row1 = nullptr;
    if (is_pred) {
        img  = pred_masks + (size_t)(b * QQ + m) * (HH * WW);
        row0 = OM + (size_t)(b * QQ + m) * PP;
        row1 = SM + (size_t)(b * QQ + m) * PP;
    } else {
        int t = m - QQ;
        img  = tgt_masks + (size_t)(b * TT + t) * (HH * WW);
        row0 = TM + (size_t)(b * TT + t) * PP;
    }
    float s0 = 0.f, s1 = 0.f;
    for (int p = tid; p < PP; p += 256) {
        int4 o = offb[p];
        float4 w = wb[p];
        float v = w.x * img[o.x] + w.y * img[o.y] + w.z * img[o.z] + w.w * img[o.w];
        if (is_pred) {
            row0[p] = (bf16_t)v;
            float sg = 1.f / (1.f + expf(-v));
            row1[p] = (bf16_t)sg;
            float sp = fmaxf(v, 0.f) + log1pf(expf(-fabsf(v)));  // stable softplus
            s0 += sp;
            s1 += sg;
        } else {
            row0[p] = (bf16_t)v;
            s0 += v;
        }
    }
    // block reduction (4 waves of 64)
    for (int o = 32; o > 0; o >>= 1) {
        s0 += __shfl_down(s0, o, 64);
        s1 += __shfl_down(s1, o, 64);
    }
    __shared__ float ra[4], rb[4];
    int wave = tid >> 6, lane = tid & 63;
    if (lane == 0) { ra[wave] = s0; rb[wave] = s1; }
    __syncthreads();
    if (tid == 0) {
        float t0 = ra[0] + ra[1] + ra[2] + ra[3];
        float t1 = rb[0] + rb[1] + rb[2] + rb[3];
        if (is_pred) {
            RS_SP[b * QQ + m] = t0;
            RS_S[b * QQ + m]  = t1;
        } else {
            RS_T[b * TT + (m - QQ)] = t0;
        }
    }
}

// ---------------- kernel 3: dual bf16 MFMA GEMM, split-K partials ----------------
// grid: (5, 5, BB*NSPLIT), block 256 (4 waves). Block tile 64x64; wave w owns rows [w*16, w*16+16).
__global__ __launch_bounds__(256) void matmul_kernel(
    const bf16_t* __restrict__ OM, const bf16_t* __restrict__ SM, const bf16_t* __restrict__ TM,
    float* __restrict__ A1P, float* __restrict__ A2P) {
    int b = blockIdx.z >> 3;
    int split = blockIdx.z & 7;
    int m0 = blockIdx.x * 64;
    int n0 = blockIdx.y * 64;
    int tid = threadIdx.x;
    int wave = tid >> 6, lane = tid & 63;
    int lrow = lane & 15, quad = lane >> 4;

    int am = min(m0 + wave * 16 + lrow, QQ - 1);
    const bf16_t* omp = OM + (size_t)(b * QQ + am) * PP;
    const bf16_t* smp = SM + (size_t)(b * QQ + am) * PP;
    const bf16_t* tp0 = TM + (size_t)(b * TT + min(n0 + 0 * 16 + lrow, TT - 1)) * PP;
    const bf16_t* tp1 = TM + (size_t)(b * TT + min(n0 + 1 * 16 + lrow, TT - 1)) * PP;
    const bf16_t* tp2 = TM + (size_t)(b * TT + min(n0 + 2 * 16 + lrow, TT - 1)) * PP;
    const bf16_t* tp3 = TM + (size_t)(b * TT + min(n0 + 3 * 16 + lrow, TT - 1)) * PP;

    int kbase = split * KSPLIT + quad * 8;
    floatx4 acc1[4] = {{0.f,0.f,0.f,0.f},{0.f,0.f,0.f,0.f},{0.f,0.f,0.f,0.f},{0.f,0.f,0.f,0.f}};
    floatx4 acc2[4] = {{0.f,0.f,0.f,0.f},{0.f,0.f,0.f,0.f},{0.f,0.f,0.f,0.f},{0.f,0.f,0.f,0.f}};

    for (int ks = 0; ks < KSTEPS; ++ks) {
        int k = kbase + ks * 32;
        bf16x8 a1 = *(const bf16x8*)(omp + k);
        bf16x8 a2 = *(const bf16x8*)(smp + k);
        bf16x8 b0 = *(const bf16x8*)(tp0 + k);
        bf16x8 b1 = *(const bf16x8*)(tp1 + k);
        bf16x8 b2 = *(const bf16x8*)(tp2 + k);
        bf16x8 b3 = *(const bf16x8*)(tp3 + k);
        acc1[0] = __builtin_amdgcn_mfma_f32_16x16x32_bf16(a1, b0, acc1[0], 0, 0, 0);
        acc2[0] = __builtin_amdgcn_mfma_f32_16x16x32_bf16(a2, b0, acc2[0], 0, 0, 0);
        acc1[1] = __builtin_amdgcn_mfma_f32_16x16x32_bf16(a1, b1, acc1[1], 0, 0, 0);
        acc2[1] = __builtin_amdgcn_mfma_f32_16x16x32_bf16(a2, b1, acc2[1], 0, 0, 0);
        acc1[2] = __builtin_amdgcn_mfma_f32_16x16x32_bf16(a1, b2, acc1[2], 0, 0, 0);
        acc2[2] = __builtin_amdgcn_mfma_f32_16x16x32_bf16(a2, b2, acc2[2], 0, 0, 0);
        acc1[3] = __builtin_amdgcn_mfma_f32_16x16x32_bf16(a1, b3, acc1[3], 0, 0, 0);
        acc2[3] = __builtin_amdgcn_mfma_f32_16x16x32_bf16(a2, b3, acc2[3], 0, 0, 0);
    }

    // C/D layout (verified m89/m91): col = lane&15, row = quad*4 + reg
    int mrow = m0 + wave * 16 + quad * 4;
    float* o1 = A1P + (size_t)(b * NSPLIT + split) * (QQ * TT);
    float* o2 = A2P + (size_t)(b * NSPLIT + split) * (QQ * TT);
    for (int j = 0; j < 4; ++j) {
        int n = n0 + j * 16 + lrow;
        if (n < TT) {
            for (int r = 0; r < 4; ++r) {
                int m = mrow + r;
                if (m < QQ) {
                    o1[m * TT + n] = acc1[j][r];
                    o2[m * TT + n] = acc2[j][r];
                }
            }
        }
    }
}

// ---------------- kernel 4: reduce splits + mask/dice/bbox/giou combine ----------------
__global__ __launch_bounds__(256) void combine_kernel(
    const float* __restrict__ A1P, const float* __restrict__ A2P,
    const float* __restrict__ RS_SP, const float* __restrict__ RS_S, const float* __restrict__ RS_T,
    const float* __restrict__ pred_boxes, const float* __restrict__ tgt_boxes,
    float* __restrict__ out) {
    int idx = blockIdx.x * 256 + threadIdx.x;
    if (idx >= BB * QQ * TT) return;
    int b = idx / (QQ * TT);
    int r = idx - b * (QQ * TT);
    int q = r / TT;
    int t = r - q * TT;

    float a1 = 0.f, a2 = 0.f;
    for (int s = 0; s < NSPLIT; ++s) {
        a1 += A1P[(size_t)(b * NSPLIT + s) * (QQ * TT) + r];
        a2 += A2P[(size_t)(b * NSPLIT + s) * (QQ * TT) + r];
    }
    // cost_mask = (sum_p softplus(om) - om.tm) / P
    float cm = (RS_SP[b * QQ + q] - a1) * (1.0f / (float)PP);
    // cost_dice = 1 - (2*s.tm + 1)/(sum s + sum tm + 1)
    float cd = 1.f - (2.f * a2 + 1.f) / (RS_S[b * QQ + q] + RS_T[b * TT + t] + 1.f);

    const float* pb = pred_boxes + (size_t)(b * QQ + q) * 4;
    const float* tb = tgt_boxes + (size_t)(b * TT + t) * 4;
    float cb = fabsf(pb[0] - tb[0]) + fabsf(pb[1] - tb[1]) +
               fabsf(pb[2] - tb[2]) + fabsf(pb[3] - tb[3]);

    float ax0 = pb[0] - 0.5f * pb[2], ay0 = pb[1] - 0.5f * pb[3];
    float ax1 = pb[0] + 0.5f * pb[2], ay1 = pb[1] + 0.5f * pb[3];
    float bx0 = tb[0] - 0.5f * tb[2], by0 = tb[1] - 0.5f * tb[3];
    float bx1 = tb[0] + 0.5f * tb[2], by1 = tb[1] + 0.5f * tb[3];
    float area_a = (ax1 - ax0) * (ay1 - ay0);
    float area_b = (bx1 - bx0) * (by1 - by0);
    float iw = fmaxf(fminf(ax1, bx1) - fmaxf(ax0, bx0), 0.f);
    float ih = fmaxf(fminf(ay1, by1) - fmaxf(ay0, by0), 0.f);
    float inter = iw * ih;
    float uni = area_a + area_b - inter;
    float iou = inter / uni;
    float ew = fmaxf(ax1, bx1) - fminf(ax0, bx0);
    float eh = fmaxf(ay1, by1) - fminf(ay0, by0);
    float area_e = ew * eh;
    float giou = iou - (area_e - uni) / area_e;

    out[idx] = 5.f * cm + 5.f * cd + 5.f * cb - 2.f * giou;
}

extern "C" void kernel_launch(void* const* d_in, const int* in_sizes, int n_in,
                              void* d_out, int out_size, void* d_ws, size_t ws_size,
                              hipStream_t stream) {
    const float* pred_masks = (const float*)d_in[0];
    const float* tgt_masks  = (const float*)d_in[1];
    const float* pred_boxes = (const float*)d_in[2];
    const float* tgt_boxes  = (const float*)d_in[3];
    const float* pts        = (const float*)d_in[4];

    char* w = (char*)d_ws;
    auto alloc = [&](size_t bytes) -> char* {
        char* r = w;
        w += (bytes + 255) & ~(size_t)255;
        return r;
    };
    int4*   OFF  = (int4*)  alloc((size_t)BB * PP * sizeof(int4));
    float4* WGT  = (float4*)alloc((size_t)BB * PP * sizeof(float4));
    bf16_t* OM   = (bf16_t*)alloc((size_t)BB * QQ * PP * 2);
    bf16_t* SM   = (bf16_t*)alloc((size_t)BB * QQ * PP * 2);
    bf16_t* TM   = (bf16_t*)alloc((size_t)BB * TT * PP * 2);
    float*  RS_SP = (float*)alloc((size_t)BB * QQ * 4);
    float*  RS_S  = (float*)alloc((size_t)BB * QQ * 4);
    float*  RS_T  = (float*)alloc((size_t)BB * TT * 4);
    float*  A1P  = (float*) alloc((size_t)BB * NSPLIT * QQ * TT * 4);
    float*  A2P  = (float*) alloc((size_t)BB * NSPLIT * QQ * TT * 4);

    prep_kernel<<<(BB * PP + 255) / 256, 256, 0, stream>>>(pts, OFF, WGT);
    sample_kernel<<<dim3(QQ + TT, BB), 256, 0, stream>>>(
        pred_masks, tgt_masks, OFF, WGT, OM, SM, TM, RS_SP, RS_S, RS_T);
    matmul_kernel<<<dim3(5, 5, BB * NSPLIT), 256, 0, stream>>>(OM, SM, TM, A1P, A2P);
    combine_kernel<<<(BB * QQ * TT + 255) / 256, 256, 0, stream>>>(
        A1P, A2P, RS_SP, RS_S, RS_T, pred_boxes, tgt_boxes, (float*)d_out);
}

// Round 3
// 473.081 us; speedup vs baseline: 1.6690x; 1.6690x over previous
//
#include <hip/hip_runtime.h>
#include <hip/hip_bf16.h>
#include <math.h>

#define BB 2
#define QQ 300
#define TT 300
#define HH 256
#define WW 256
#define PP 12544
#define NSPLIT 14
#define KSPLIT (PP / NSPLIT)          // 896
#define KSTEPS (KSPLIT / 64)          // 14 steps of BK=64

typedef __bf16 bf16_t;
typedef bf16_t bf16x8 __attribute__((ext_vector_type(8)));
typedef float floatx4 __attribute__((ext_vector_type(4)));

__device__ inline void gl_lds16(const void* g, void* l) {
    __builtin_amdgcn_global_load_lds(
        (const __attribute__((address_space(1))) unsigned int*)g,
        (__attribute__((address_space(3))) unsigned int*)l, 16, 0, 0);
}

// ---------------- kernel 1: per-point bilinear offsets/weights + row bucket ----------------
__global__ __launch_bounds__(256) void prep_kernel(const float* __restrict__ pts,
                                                   int4* __restrict__ off,
                                                   float4* __restrict__ wgt,
                                                   int* __restrict__ bkt) {
    int idx = blockIdx.x * 256 + threadIdx.x;
    if (idx >= BB * PP) return;
    float px = pts[idx * 2 + 0];
    float py = pts[idx * 2 + 1];
    float x = px * WW - 0.5f;
    float y = py * HH - 0.5f;
    float x0f = floorf(x), y0f = floorf(y);
    float wx = x - x0f, wy = y - y0f;
    int x0 = (int)x0f, y0 = (int)y0f;
    int x1 = x0 + 1, y1 = y0 + 1;
    float vx0 = (x0 >= 0 && x0 < WW) ? 1.f : 0.f;
    float vx1 = (x1 >= 0 && x1 < WW) ? 1.f : 0.f;
    float vy0 = (y0 >= 0 && y0 < HH) ? 1.f : 0.f;
    float vy1 = (y1 >= 0 && y1 < HH) ? 1.f : 0.f;
    int cx0 = min(max(x0, 0), WW - 1), cx1 = min(max(x1, 0), WW - 1);
    int cy0 = min(max(y0, 0), HH - 1), cy1 = min(max(y1, 0), HH - 1);
    off[idx] = make_int4(cy0 * WW + cx0, cy0 * WW + cx1, cy1 * WW + cx0, cy1 * WW + cx1);
    wgt[idx] = make_float4((1.f - wy) * (1.f - wx) * vy0 * vx0,
                           (1.f - wy) * wx        * vy0 * vx1,
                           wy        * (1.f - wx) * vy1 * vx0,
                           wy        * wx         * vy1 * vx1);
    // bucket by clamped y0: rows needed are within [bucket, bucket+1]
    bkt[idx] = min(max(y0, 0), HH - 2);
}

// ---------------- kernel 1b: counting-sort points by bucket (per batch) ----------------
// Consistently permuting the P axis of OM/SM/TM leaves all dot products / sums invariant.
__global__ __launch_bounds__(256) void sort_kernel(const int4* __restrict__ off,
                                                   const float4* __restrict__ wgt,
                                                   const int* __restrict__ bkt,
                                                   int4* __restrict__ off_s,
                                                   float4* __restrict__ wgt_s,
                                                   int* __restrict__ cs) {
    int b = blockIdx.x;
    int tid = threadIdx.x;
    __shared__ int hist[256];
    __shared__ int base_s[256];
    hist[tid] = 0;
    __syncthreads();
    for (int p = tid; p < PP; p += 256) atomicAdd(&hist[bkt[b * PP + p]], 1);
    __syncthreads();
    if (tid == 0) {
        int run = 0;
        for (int i = 0; i < 256; ++i) { base_s[i] = run; run += hist[i]; }
    }
    __syncthreads();
    if (tid < 9) cs[b * 9 + tid] = (tid < 8) ? base_s[tid * 32] : PP;
    __syncthreads();
    for (int p = tid; p < PP; p += 256) {
        int bp = b * PP + p;
        int pos = atomicAdd(&base_s[bkt[bp]], 1);
        off_s[b * PP + pos] = off[bp];
        wgt_s[b * PP + pos] = wgt[bp];
    }
}

// ---------------- kernel 2: point-sample via LDS row staging ----------------
// One block per mask image. Image is streamed coalesced ONCE (32-row chunks + 1 overlap
// row into LDS); bucketed points gather from LDS.
__global__ __launch_bounds__(256) void sample_kernel(
    const float* __restrict__ pred_masks, const float* __restrict__ tgt_masks,
    const int4* __restrict__ off_s, const float4* __restrict__ wgt_s,
    const int* __restrict__ cs_g,
    bf16_t* __restrict__ OM, bf16_t* __restrict__ SM, bf16_t* __restrict__ TM,
    float* __restrict__ RS_SP, float* __restrict__ RS_S, float* __restrict__ RS_T) {
    int b = blockIdx.y;
    int m = blockIdx.x;  // 0..QQ+TT-1
    int tid = threadIdx.x;
    __shared__ float rows[33 * 256];
    const int4*  offb = off_s + b * PP;
    const float4* wb  = wgt_s + b * PP;
    const int* cs = cs_g + b * 9;
    bool is_pred = (m < QQ);
    const float* img;
    bf16_t* row0;
    bf16_t* row1 = nullptr;
    if (is_pred) {
        img  = pred_masks + (size_t)(b * QQ + m) * (HH * WW);
        row0 = OM + (size_t)(b * QQ + m) * PP;
        row1 = SM + (size_t)(b * QQ + m) * PP;
    } else {
        int t = m - QQ;
        img  = tgt_masks + (size_t)(b * TT + t) * (HH * WW);
        row0 = TM + (size_t)(b * TT + t) * PP;
    }
    float s0 = 0.f, s1 = 0.f;
    for (int c = 0; c < 8; ++c) {
        int base = c * 32;
        int n4 = min(33, HH - base) * (WW / 4);   // float4 count (33 rows, 32 for last chunk)
        const float4* img4 = (const float4*)(img + base * WW);
        float4* rows4 = (float4*)rows;
        for (int i = tid; i < n4; i += 256) rows4[i] = img4[i];
        __syncthreads();
        int boff = base * WW;
        int j1 = cs[c + 1];
        for (int j = cs[c] + tid; j < j1; j += 256) {
            int4 o = offb[j];
            float4 w = wb[j];
            float v = w.x * rows[o.x - boff] + w.y * rows[o.y - boff] +
                      w.z * rows[o.z - boff] + w.w * rows[o.w - boff];
            row0[j] = (bf16_t)v;
            if (is_pred) {
                float sg = 1.f / (1.f + expf(-v));
                row1[j] = (bf16_t)sg;
                float sp = fmaxf(v, 0.f) + log1pf(expf(-fabsf(v)));
                s0 += sp;
                s1 += sg;
            } else {
                s0 += v;
            }
        }
        __syncthreads();
    }
    for (int o = 32; o > 0; o >>= 1) {
        s0 += __shfl_down(s0, o, 64);
        s1 += __shfl_down(s1, o, 64);
    }
    __shared__ float ra[4], rb[4];
    int wave = tid >> 6, lane = tid & 63;
    if (lane == 0) { ra[wave] = s0; rb[wave] = s1; }
    __syncthreads();
    if (tid == 0) {
        float t0 = ra[0] + ra[1] + ra[2] + ra[3];
        float t1 = rb[0] + rb[1] + rb[2] + rb[3];
        if (is_pred) {
            RS_SP[b * QQ + m] = t0;
            RS_S[b * QQ + m]  = t1;
        } else {
            RS_T[b * TT + (m - QQ)] = t0;
        }
    }
}

// ---------------- kernel 3: LDS-staged dual bf16 MFMA GEMM, split-K ----------------
// 64x64 tile, BK=64, global_load_lds width-16 staging, XOR chunk swizzle.
// Single LDS array (mat*4096 offsets) to avoid addrspacecast-in-static-initializer.
__global__ __launch_bounds__(256) void matmul_kernel(
    const bf16_t* __restrict__ OM, const bf16_t* __restrict__ SM, const bf16_t* __restrict__ TM,
    float* __restrict__ A1P, float* __restrict__ A2P) {
    int b = blockIdx.z / NSPLIT;
    int split = blockIdx.z % NSPLIT;
    int m0 = blockIdx.x * 64;
    int n0 = blockIdx.y * 64;
    int tid = threadIdx.x;
    int wave = tid >> 6, lane = tid & 63;
    int lrow = lane & 15, quad = lane >> 4;

    __shared__ __align__(16) bf16_t lds[3 * 64 * 64];   // [A1 | A2 | B]

    int k0 = split * KSPLIT;
    int lr8 = lane >> 3;           // row within 8-row group
    int clog = (lane & 7) ^ lr8;   // swizzled logical chunk this lane fetches

    const char* gp[6];
    unsigned lofs[6];
#pragma unroll
    for (int jj = 0; jj < 6; ++jj) {
        int L = wave + jj * 4;     // 24 wave-loads: 3 matrices x 8 row-groups
        int mat = L >> 3, i = L & 7;
        int rb_ = (mat == 2) ? n0 : m0;
        int row = min(rb_ + i * 8 + lr8, (mat == 2) ? (TT - 1) : (QQ - 1));
        const bf16_t* g = (mat == 0) ? OM + (size_t)b * QQ * PP
                        : (mat == 1) ? SM + (size_t)b * QQ * PP
                                     : TM + (size_t)b * TT * PP;
        gp[jj] = (const char*)(g + (size_t)row * PP + k0) + clog * 16;
        lofs[jj] = mat * 4096 + i * 512;   // 8 rows x 64 bf16 per group
    }

    floatx4 acc1[4] = {{0.f,0.f,0.f,0.f},{0.f,0.f,0.f,0.f},{0.f,0.f,0.f,0.f},{0.f,0.f,0.f,0.f}};
    floatx4 acc2[4] = {{0.f,0.f,0.f,0.f},{0.f,0.f,0.f,0.f},{0.f,0.f,0.f,0.f},{0.f,0.f,0.f,0.f}};

    int ar = wave * 16 + lrow;
    int arx = ar & 7;
    for (int s = 0; s < KSTEPS; ++s) {
#pragma unroll
        for (int jj = 0; jj < 6; ++jj) {
            gl_lds16(gp[jj], lds + lofs[jj]);
            gp[jj] += 128;   // 64 bf16
        }
        __syncthreads();
#pragma unroll
        for (int kk8 = 0; kk8 <= 4; kk8 += 4) {   // two K=32 halves of BK=64
            bf16x8 a1 = *(const bf16x8*)(lds + ar * 64 + (((quad + kk8) ^ arx) << 3));
            bf16x8 a2 = *(const bf16x8*)(lds + 4096 + ar * 64 + (((quad + kk8) ^ arx) << 3));
#pragma unroll
            for (int j = 0; j < 4; ++j) {
                int br = j * 16 + lrow;
                bf16x8 bb = *(const bf16x8*)(lds + 8192 + br * 64 + (((quad + kk8) ^ (br & 7)) << 3));
                acc1[j] = __builtin_amdgcn_mfma_f32_16x16x32_bf16(a1, bb, acc1[j], 0, 0, 0);
                acc2[j] = __builtin_amdgcn_mfma_f32_16x16x32_bf16(a2, bb, acc2[j], 0, 0, 0);
            }
        }
        __syncthreads();
    }

    // C/D layout: col = lane&15, row = quad*4 + reg
    int mrow = m0 + wave * 16 + quad * 4;
    float* o1 = A1P + (size_t)(b * NSPLIT + split) * (QQ * TT);
    float* o2 = A2P + (size_t)(b * NSPLIT + split) * (QQ * TT);
#pragma unroll
    for (int j = 0; j < 4; ++j) {
        int n = n0 + j * 16 + lrow;
        if (n < TT) {
#pragma unroll
            for (int r = 0; r < 4; ++r) {
                int m = mrow + r;
                if (m < QQ) {
                    o1[m * TT + n] = acc1[j][r];
                    o2[m * TT + n] = acc2[j][r];
                }
            }
        }
    }
}

// ---------------- kernel 4: reduce splits + mask/dice/bbox/giou combine ----------------
__global__ __launch_bounds__(256) void combine_kernel(
    const float* __restrict__ A1P, const float* __restrict__ A2P,
    const float* __restrict__ RS_SP, const float* __restrict__ RS_S, const float* __restrict__ RS_T,
    const float* __restrict__ pred_boxes, const float* __restrict__ tgt_boxes,
    float* __restrict__ out) {
    int idx = blockIdx.x * 256 + threadIdx.x;
    if (idx >= BB * QQ * TT) return;
    int b = idx / (QQ * TT);
    int r = idx - b * (QQ * TT);
    int q = r / TT;
    int t = r - q * TT;

    float a1 = 0.f, a2 = 0.f;
    for (int s = 0; s < NSPLIT; ++s) {
        a1 += A1P[(size_t)(b * NSPLIT + s) * (QQ * TT) + r];
        a2 += A2P[(size_t)(b * NSPLIT + s) * (QQ * TT) + r];
    }
    float cm = (RS_SP[b * QQ + q] - a1) * (1.0f / (float)PP);
    float cd = 1.f - (2.f * a2 + 1.f) / (RS_S[b * QQ + q] + RS_T[b * TT + t] + 1.f);

    const float* pb = pred_boxes + (size_t)(b * QQ + q) * 4;
    const float* tb = tgt_boxes + (size_t)(b * TT + t) * 4;
    float cb = fabsf(pb[0] - tb[0]) + fabsf(pb[1] - tb[1]) +
               fabsf(pb[2] - tb[2]) + fabsf(pb[3] - tb[3]);

    float ax0 = pb[0] - 0.5f * pb[2], ay0 = pb[1] - 0.5f * pb[3];
    float ax1 = pb[0] + 0.5f * pb[2], ay1 = pb[1] + 0.5f * pb[3];
    float bx0 = tb[0] - 0.5f * tb[2], by0 = tb[1] - 0.5f * tb[3];
    float bx1 = tb[0] + 0.5f * tb[2], by1 = tb[1] + 0.5f * tb[3];
    float area_a = (ax1 - ax0) * (ay1 - ay0);
    float area_b = (bx1 - bx0) * (by1 - by0);
    float iw = fmaxf(fminf(ax1, bx1) - fmaxf(ax0, bx0), 0.f);
    float ih = fmaxf(fminf(ay1, by1) - fmaxf(ay0, by0), 0.f);
    float inter = iw * ih;
    float uni = area_a + area_b - inter;
    float iou = inter / uni;
    float ew = fmaxf(ax1, bx1) - fminf(ax0, bx0);
    float eh = fmaxf(ay1, by1) - fminf(ay0, by0);
    float area_e = ew * eh;
    float giou = iou - (area_e - uni) / area_e;

    out[idx] = 5.f * cm + 5.f * cd + 5.f * cb - 2.f * giou;
}

extern "C" void kernel_launch(void* const* d_in, const int* in_sizes, int n_in,
                              void* d_out, int out_size, void* d_ws, size_t ws_size,
                              hipStream_t stream) {
    const float* pred_masks = (const float*)d_in[0];
    const float* tgt_masks  = (const float*)d_in[1];
    const float* pred_boxes = (const float*)d_in[2];
    const float* tgt_boxes  = (const float*)d_in[3];
    const float* pts        = (const float*)d_in[4];

    char* w = (char*)d_ws;
    auto alloc = [&](size_t bytes) -> char* {
        char* r = w;
        w += (bytes + 255) & ~(size_t)255;
        return r;
    };
    int4*   OFF   = (int4*)  alloc((size_t)BB * PP * sizeof(int4));
    float4* WGT   = (float4*)alloc((size_t)BB * PP * sizeof(float4));
    int*    BKT   = (int*)   alloc((size_t)BB * PP * sizeof(int));
    int4*   OFF_S = (int4*)  alloc((size_t)BB * PP * sizeof(int4));
    float4* WGT_S = (float4*)alloc((size_t)BB * PP * sizeof(float4));
    int*    CS    = (int*)   alloc((size_t)BB * 9 * sizeof(int));
    bf16_t* OM    = (bf16_t*)alloc((size_t)BB * QQ * PP * 2);
    bf16_t* SM    = (bf16_t*)alloc((size_t)BB * QQ * PP * 2);
    bf16_t* TM    = (bf16_t*)alloc((size_t)BB * TT * PP * 2);
    float*  RS_SP = (float*) alloc((size_t)BB * QQ * 4);
    float*  RS_S  = (float*) alloc((size_t)BB * QQ * 4);
    float*  RS_T  = (float*) alloc((size_t)BB * TT * 4);
    float*  A1P   = (float*) alloc((size_t)BB * NSPLIT * QQ * TT * 4);
    float*  A2P   = (float*) alloc((size_t)BB * NSPLIT * QQ * TT * 4);

    prep_kernel<<<(BB * PP + 255) / 256, 256, 0, stream>>>(pts, OFF, WGT, BKT);
    sort_kernel<<<BB, 256, 0, stream>>>(OFF, WGT, BKT, OFF_S, WGT_S, CS);
    sample_kernel<<<dim3(QQ + TT, BB), 256, 0, stream>>>(
        pred_masks, tgt_masks, OFF_S, WGT_S, CS, OM, SM, TM, RS_SP, RS_S, RS_T);
    matmul_kernel<<<dim3(5, 5, BB * NSPLIT), 256, 0, stream>>>(OM, SM, TM, A1P, A2P);
    combine_kernel<<<(BB * QQ * TT + 255) / 256, 256, 0, stream>>>(
        A1P, A2P, RS_SP, RS_S, RS_T, pred_boxes, tgt_boxes, (float*)d_out);
}

// Round 4
// 395.623 us; speedup vs baseline: 1.9958x; 1.1958x over previous
//
#include <hip/hip_runtime.h>
#include <hip/hip_bf16.h>
#include <math.h>

#define BB 2
#define QQ 300
#define TT 300
#define HH 256
#define WW 256
#define PP 12544
#define NCHUNK 16                     // 16-row y-buckets
#define NSPLIT 14
#define KSPLIT (PP / NSPLIT)          // 896
#define KSTEPS (KSPLIT / 64)          // 14 steps of BK=64

typedef __bf16 bf16_t;
typedef bf16_t bf16x8 __attribute__((ext_vector_type(8)));
typedef float floatx4 __attribute__((ext_vector_type(4)));

__device__ inline void gl_lds16(const void* g, void* l) {
    __builtin_amdgcn_global_load_lds(
        (const __attribute__((address_space(1))) unsigned int*)g,
        (__attribute__((address_space(3))) unsigned int*)l, 16, 0, 0);
}

// ---------------- kernel 1: per-point bilinear offsets/weights + 16-row bucket ----------------
__global__ __launch_bounds__(256) void prep_kernel(const float* __restrict__ pts,
                                                   int4* __restrict__ off,
                                                   float4* __restrict__ wgt,
                                                   int* __restrict__ bkt) {
    int idx = blockIdx.x * 256 + threadIdx.x;
    if (idx >= BB * PP) return;
    float px = pts[idx * 2 + 0];
    float py = pts[idx * 2 + 1];
    float x = px * WW - 0.5f;
    float y = py * HH - 0.5f;
    float x0f = floorf(x), y0f = floorf(y);
    float wx = x - x0f, wy = y - y0f;
    int x0 = (int)x0f, y0 = (int)y0f;
    int x1 = x0 + 1, y1 = y0 + 1;
    float vx0 = (x0 >= 0 && x0 < WW) ? 1.f : 0.f;
    float vx1 = (x1 >= 0 && x1 < WW) ? 1.f : 0.f;
    float vy0 = (y0 >= 0 && y0 < HH) ? 1.f : 0.f;
    float vy1 = (y1 >= 0 && y1 < HH) ? 1.f : 0.f;
    int cx0 = min(max(x0, 0), WW - 1), cx1 = min(max(x1, 0), WW - 1);
    int cy0 = min(max(y0, 0), HH - 1), cy1 = min(max(y1, 0), HH - 1);
    off[idx] = make_int4(cy0 * WW + cx0, cy0 * WW + cx1, cy1 * WW + cx0, cy1 * WW + cx1);
    wgt[idx] = make_float4((1.f - wy) * (1.f - wx) * vy0 * vx0,
                           (1.f - wy) * wx        * vy0 * vx1,
                           wy        * (1.f - wx) * vy1 * vx0,
                           wy        * wx         * vy1 * vx1);
    // clamped y0 in [0,254]; rows y0,y0+1 lie in [16c, 16c+16] for bucket c=y0>>4
    bkt[idx] = min(max(y0, 0), HH - 2) >> 4;
}

// ---------------- kernel 1b: counting-sort points into 16 y-buckets (per batch) ----------------
__global__ __launch_bounds__(1024) void sort_kernel(const int4* __restrict__ off,
                                                    const float4* __restrict__ wgt,
                                                    const int* __restrict__ bkt,
                                                    int4* __restrict__ off_s,
                                                    float4* __restrict__ wgt_s,
                                                    int* __restrict__ cs) {
    int b = blockIdx.x;
    int tid = threadIdx.x;
    __shared__ int hist[NCHUNK];
    __shared__ int base_s[NCHUNK];
    if (tid < NCHUNK) hist[tid] = 0;
    __syncthreads();
    for (int p = tid; p < PP; p += 1024) atomicAdd(&hist[bkt[b * PP + p]], 1);
    __syncthreads();
    if (tid == 0) {
        int run = 0;
        for (int i = 0; i < NCHUNK; ++i) { base_s[i] = run; run += hist[i]; }
    }
    __syncthreads();
    if (tid < NCHUNK + 1) cs[b * (NCHUNK + 1) + tid] = (tid < NCHUNK) ? base_s[tid] : PP;
    __syncthreads();
    for (int p = tid; p < PP; p += 1024) {
        int bp = b * PP + p;
        int pos = atomicAdd(&base_s[bkt[bp]], 1);
        off_s[b * PP + pos] = off[bp];
        wgt_s[b * PP + pos] = wgt[bp];
    }
}

// ---------------- kernel 2: point-sample; one block per (mask, chunk) ----------------
// Each block async-stages its 17-row window into LDS via global_load_lds (no reg
// round-trip) and gathers only its bucket's points. Row sums via atomicAdd partials.
__global__ __launch_bounds__(256) void sample_kernel(
    const float* __restrict__ pred_masks, const float* __restrict__ tgt_masks,
    const int4* __restrict__ off_s, const float4* __restrict__ wgt_s,
    const int* __restrict__ cs_g,
    bf16_t* __restrict__ OM, bf16_t* __restrict__ SM, bf16_t* __restrict__ TM,
    float* __restrict__ RS_SP, float* __restrict__ RS_S, float* __restrict__ RS_T) {
    int b = blockIdx.z;
    int m = blockIdx.x;  // 0..QQ+TT-1
    int c = blockIdx.y;  // chunk
    int tid = threadIdx.x;
    int wave = tid >> 6, lane = tid & 63;
    __shared__ __align__(16) float rows[17 * WW];

    bool is_pred = (m < QQ);
    const float* img;
    bf16_t* row0;
    bf16_t* row1 = nullptr;
    if (is_pred) {
        img  = pred_masks + (size_t)(b * QQ + m) * (HH * WW);
        row0 = OM + (size_t)(b * QQ + m) * PP;
        row1 = SM + (size_t)(b * QQ + m) * PP;
    } else {
        int t = m - QQ;
        img  = tgt_masks + (size_t)(b * TT + t) * (HH * WW);
        row0 = TM + (size_t)(b * TT + t) * PP;
    }

    int base = c * 16;
    int nrows = min(17, HH - base);        // 17, except 16 for the last chunk
    const char* gimg = (const char*)(img + base * WW);
    // one row = 256 floats = 1024 B = one wave-issue (64 lanes x 16 B)
    for (int i = wave; i < nrows; i += 4)
        gl_lds16(gimg + i * 1024 + lane * 16, (char*)rows + i * 1024);
    __syncthreads();

    const int4*  offb = off_s + b * PP;
    const float4* wb  = wgt_s + b * PP;
    const int* cs = cs_g + b * (NCHUNK + 1);
    int boff = base * WW;
    int j1 = cs[c + 1];
    float s0 = 0.f, s1 = 0.f;
    for (int j = cs[c] + tid; j < j1; j += 256) {
        int4 o = offb[j];
        float4 w = wb[j];
        float v = w.x * rows[o.x - boff] + w.y * rows[o.y - boff] +
                  w.z * rows[o.z - boff] + w.w * rows[o.w - boff];
        row0[j] = (bf16_t)v;
        if (is_pred) {
            float e = __expf(-fabsf(v));
            float r = 1.f / (1.f + e);
            float sg = (v >= 0.f) ? r : e * r;
            row1[j] = (bf16_t)sg;
            s0 += fmaxf(v, 0.f) + __logf(1.f + e);   // stable softplus
            s1 += sg;
        } else {
            s0 += v;
        }
    }
    for (int o = 32; o > 0; o >>= 1) {
        s0 += __shfl_down(s0, o, 64);
        s1 += __shfl_down(s1, o, 64);
    }
    __shared__ float ra[4], rb[4];
    if (lane == 0) { ra[wave] = s0; rb[wave] = s1; }
    __syncthreads();
    if (tid == 0) {
        float t0 = ra[0] + ra[1] + ra[2] + ra[3];
        float t1 = rb[0] + rb[1] + rb[2] + rb[3];
        if (is_pred) {
            atomicAdd(&RS_SP[b * QQ + m], t0);
            atomicAdd(&RS_S[b * QQ + m], t1);
        } else {
            atomicAdd(&RS_T[b * TT + (m - QQ)], t0);
        }
    }
}

// ---------------- kernel 3: LDS-staged dual bf16 MFMA GEMM, split-K ----------------
__global__ __launch_bounds__(256) void matmul_kernel(
    const bf16_t* __restrict__ OM, const bf16_t* __restrict__ SM, const bf16_t* __restrict__ TM,
    float* __restrict__ A1P, float* __restrict__ A2P) {
    int b = blockIdx.z / NSPLIT;
    int split = blockIdx.z % NSPLIT;
    int m0 = blockIdx.x * 64;
    int n0 = blockIdx.y * 64;
    int tid = threadIdx.x;
    int wave = tid >> 6, lane = tid & 63;
    int lrow = lane & 15, quad = lane >> 4;

    __shared__ __align__(16) bf16_t lds[3 * 64 * 64];   // [A1 | A2 | B]

    int k0 = split * KSPLIT;
    int lr8 = lane >> 3;           // row within 8-row group
    int clog = (lane & 7) ^ lr8;   // swizzled logical chunk this lane fetches

    const char* gp[6];
    unsigned lofs[6];
#pragma unroll
    for (int jj = 0; jj < 6; ++jj) {
        int L = wave + jj * 4;     // 24 wave-loads: 3 matrices x 8 row-groups
        int mat = L >> 3, i = L & 7;
        int rb_ = (mat == 2) ? n0 : m0;
        int row = min(rb_ + i * 8 + lr8, (mat == 2) ? (TT - 1) : (QQ - 1));
        const bf16_t* g = (mat == 0) ? OM + (size_t)b * QQ * PP
                        : (mat == 1) ? SM + (size_t)b * QQ * PP
                                     : TM + (size_t)b * TT * PP;
        gp[jj] = (const char*)(g + (size_t)row * PP + k0) + clog * 16;
        lofs[jj] = mat * 4096 + i * 512;   // 8 rows x 64 bf16 per group
    }

    floatx4 acc1[4] = {{0.f,0.f,0.f,0.f},{0.f,0.f,0.f,0.f},{0.f,0.f,0.f,0.f},{0.f,0.f,0.f,0.f}};
    floatx4 acc2[4] = {{0.f,0.f,0.f,0.f},{0.f,0.f,0.f,0.f},{0.f,0.f,0.f,0.f},{0.f,0.f,0.f,0.f}};

    int ar = wave * 16 + lrow;
    int arx = ar & 7;
    for (int s = 0; s < KSTEPS; ++s) {
#pragma unroll
        for (int jj = 0; jj < 6; ++jj) {
            gl_lds16(gp[jj], lds + lofs[jj]);
            gp[jj] += 128;   // 64 bf16
        }
        __syncthreads();
#pragma unroll
        for (int kk8 = 0; kk8 <= 4; kk8 += 4) {   // two K=32 halves of BK=64
            bf16x8 a1 = *(const bf16x8*)(lds + ar * 64 + (((quad + kk8) ^ arx) << 3));
            bf16x8 a2 = *(const bf16x8*)(lds + 4096 + ar * 64 + (((quad + kk8) ^ arx) << 3));
#pragma unroll
            for (int j = 0; j < 4; ++j) {
                int br = j * 16 + lrow;
                bf16x8 bb = *(const bf16x8*)(lds + 8192 + br * 64 + (((quad + kk8) ^ (br & 7)) << 3));
                acc1[j] = __builtin_amdgcn_mfma_f32_16x16x32_bf16(a1, bb, acc1[j], 0, 0, 0);
                acc2[j] = __builtin_amdgcn_mfma_f32_16x16x32_bf16(a2, bb, acc2[j], 0, 0, 0);
            }
        }
        __syncthreads();
    }

    // C/D layout: col = lane&15, row = quad*4 + reg
    int mrow = m0 + wave * 16 + quad * 4;
    float* o1 = A1P + (size_t)(b * NSPLIT + split) * (QQ * TT);
    float* o2 = A2P + (size_t)(b * NSPLIT + split) * (QQ * TT);
#pragma unroll
    for (int j = 0; j < 4; ++j) {
        int n = n0 + j * 16 + lrow;
        if (n < TT) {
#pragma unroll
            for (int r = 0; r < 4; ++r) {
                int m = mrow + r;
                if (m < QQ) {
                    o1[m * TT + n] = acc1[j][r];
                    o2[m * TT + n] = acc2[j][r];
                }
            }
        }
    }
}

// ---------------- kernel 4: reduce splits + mask/dice/bbox/giou combine ----------------
__global__ __launch_bounds__(256) void combine_kernel(
    const float* __restrict__ A1P, const float* __restrict__ A2P,
    const float* __restrict__ RS_SP, const float* __restrict__ RS_S, const float* __restrict__ RS_T,
    const float* __restrict__ pred_boxes, const float* __restrict__ tgt_boxes,
    float* __restrict__ out) {
    int idx = blockIdx.x * 256 + threadIdx.x;
    if (idx >= BB * QQ * TT) return;
    int b = idx / (QQ * TT);
    int r = idx - b * (QQ * TT);
    int q = r / TT;
    int t = r - q * TT;

    float a1 = 0.f, a2 = 0.f;
    for (int s = 0; s < NSPLIT; ++s) {
        a1 += A1P[(size_t)(b * NSPLIT + s) * (QQ * TT) + r];
        a2 += A2P[(size_t)(b * NSPLIT + s) * (QQ * TT) + r];
    }
    float cm = (RS_SP[b * QQ + q] - a1) * (1.0f / (float)PP);
    float cd = 1.f - (2.f * a2 + 1.f) / (RS_S[b * QQ + q] + RS_T[b * TT + t] + 1.f);

    const float* pb = pred_boxes + (size_t)(b * QQ + q) * 4;
    const float* tb = tgt_boxes + (size_t)(b * TT + t) * 4;
    float cb = fabsf(pb[0] - tb[0]) + fabsf(pb[1] - tb[1]) +
               fabsf(pb[2] - tb[2]) + fabsf(pb[3] - tb[3]);

    float ax0 = pb[0] - 0.5f * pb[2], ay0 = pb[1] - 0.5f * pb[3];
    float ax1 = pb[0] + 0.5f * pb[2], ay1 = pb[1] + 0.5f * pb[3];
    float bx0 = tb[0] - 0.5f * tb[2], by0 = tb[1] - 0.5f * tb[3];
    float bx1 = tb[0] + 0.5f * tb[2], by1 = tb[1] + 0.5f * tb[3];
    float area_a = (ax1 - ax0) * (ay1 - ay0);
    float area_b = (bx1 - bx0) * (by1 - by0);
    float iw = fmaxf(fminf(ax1, bx1) - fmaxf(ax0, bx0), 0.f);
    float ih = fmaxf(fminf(ay1, by1) - fmaxf(ay0, by0), 0.f);
    float inter = iw * ih;
    float uni = area_a + area_b - inter;
    float iou = inter / uni;
    float ew = fmaxf(ax1, bx1) - fminf(ax0, bx0);
    float eh = fmaxf(ay1, by1) - fminf(ay0, by0);
    float area_e = ew * eh;
    float giou = iou - (area_e - uni) / area_e;

    out[idx] = 5.f * cm + 5.f * cd + 5.f * cb - 2.f * giou;
}

extern "C" void kernel_launch(void* const* d_in, const int* in_sizes, int n_in,
                              void* d_out, int out_size, void* d_ws, size_t ws_size,
                              hipStream_t stream) {
    const float* pred_masks = (const float*)d_in[0];
    const float* tgt_masks  = (const float*)d_in[1];
    const float* pred_boxes = (const float*)d_in[2];
    const float* tgt_boxes  = (const float*)d_in[3];
    const float* pts        = (const float*)d_in[4];

    char* w = (char*)d_ws;
    auto alloc = [&](size_t bytes) -> char* {
        char* r = w;
        w += (bytes + 255) & ~(size_t)255;
        return r;
    };
    int4*   OFF   = (int4*)  alloc((size_t)BB * PP * sizeof(int4));
    float4* WGT   = (float4*)alloc((size_t)BB * PP * sizeof(float4));
    int*    BKT   = (int*)   alloc((size_t)BB * PP * sizeof(int));
    int4*   OFF_S = (int4*)  alloc((size_t)BB * PP * sizeof(int4));
    float4* WGT_S = (float4*)alloc((size_t)BB * PP * sizeof(float4));
    int*    CS    = (int*)   alloc((size_t)BB * (NCHUNK + 1) * sizeof(int));
    bf16_t* OM    = (bf16_t*)alloc((size_t)BB * QQ * PP * 2);
    bf16_t* SM    = (bf16_t*)alloc((size_t)BB * QQ * PP * 2);
    bf16_t* TM    = (bf16_t*)alloc((size_t)BB * TT * PP * 2);
    float*  RS_SP = (float*) alloc((size_t)BB * QQ * 4);
    float*  RS_S  = (float*) alloc((size_t)BB * QQ * 4);
    float*  RS_T  = (float*) alloc((size_t)BB * TT * 4);
    float*  A1P   = (float*) alloc((size_t)BB * NSPLIT * QQ * TT * 4);
    float*  A2P   = (float*) alloc((size_t)BB * NSPLIT * QQ * TT * 4);

    // zero the atomic-accumulated row sums (covers RS_SP..RS_T incl. alignment pads)
    hipMemsetAsync(RS_SP, 0, (size_t)((char*)A1P - (char*)RS_SP), stream);

    prep_kernel<<<(BB * PP + 255) / 256, 256, 0, stream>>>(pts, OFF, WGT, BKT);
    sort_kernel<<<BB, 1024, 0, stream>>>(OFF, WGT, BKT, OFF_S, WGT_S, CS);
    sample_kernel<<<dim3(QQ + TT, NCHUNK, BB), 256, 0, stream>>>(
        pred_masks, tgt_masks, OFF_S, WGT_S, CS, OM, SM, TM, RS_SP, RS_S, RS_T);
    matmul_kernel<<<dim3(5, 5, BB * NSPLIT), 256, 0, stream>>>(OM, SM, TM, A1P, A2P);
    combine_kernel<<<(BB * QQ * TT + 255) / 256, 256, 0, stream>>>(
        A1P, A2P, RS_SP, RS_S, RS_T, pred_boxes, tgt_boxes, (float*)d_out);
}